// Round 8
// baseline (158.448 us; speedup 1.0000x reference)
//
#include <hip/hip_runtime.h>
#include <hip/hip_bf16.h>
#include <hip/hip_cooperative_groups.h>

namespace cg = cooperative_groups;

#define BATCH 8
#define SEQ   4096
#define NST   512     // state dim == GEMM K
#define DM    512     // d_model  == GEMM N
#define NCHUNK 32
#define TCH    128    // SEQ / NCHUNK
#define LDP    (NST + 8)   // LDS row pitch in shorts

typedef __attribute__((ext_vector_type(4))) float f32x4;
typedef __attribute__((ext_vector_type(2))) float f32x2;
typedef __attribute__((ext_vector_type(8))) short short8v;   // 8 bf16
typedef __attribute__((ext_vector_type(4))) short short4v;

__device__ __forceinline__ short f2bf(float f) {
  union { float f; unsigned u; } v; v.f = f;
  unsigned r = v.u + 0x7FFFu + ((v.u >> 16) & 1u);   // RNE truncate to bf16
  return (short)(r >> 16);
}
__device__ __forceinline__ float bf2f(short s) {
  union { unsigned u; float f; } v; v.u = ((unsigned)(unsigned short)s) << 16;
  return v.f;
}

// ============================ MEGA (cooperative) ============================
// transQ (blocks 0-63) -> local scan streamed to LDS bf16 -> grid.sync
// -> per-block prefix from S -> in-LDS correction -> TWO-PASS GEMM -> y.
// Rounds 5-7: allocator pins 512-thread kernels at 128 VGPRs (launch_bounds
// second arg had no effect); acc[8][4] spilled into the MFMA loop (+25MB
// scratch WRITE, MfmaUtil 4.5%). Fix: two 64-row passes with acc[4][4]
// (round-4 measured 92 VGPRs for this exact shape) -> fits under 128, no spill.
__global__ __launch_bounds__(512) void k_mega(
    const float* __restrict__ u, const float* __restrict__ Lam,
    const float* __restrict__ Bv, const float* __restrict__ log_dt,
    const float* __restrict__ Q, float* __restrict__ S,
    short* __restrict__ Qt, float* __restrict__ y) {
  __shared__ __align__(16) short X[TCH][LDP];     // 133120 B -> 1 block/CU
  const int tid = threadIdx.x;
  const int b = blockIdx.x & (BATCH - 1);
  const int c = blockIdx.x >> 3;

  // ---- phase 0: transQ, blocks 0..63
  if (blockIdx.x < 64) {
    short (*tile)[68] = (short(*)[68])&X[0][0];
    const int bn = (blockIdx.x & 7) * 64;
    const int bd = (blockIdx.x >> 3) * 64;
    const int tc4 = (tid & 15) * 4;
    const int tr = tid >> 4;                      // 0..31
    #pragma unroll
    for (int i = 0; i < 2; ++i) {
      int r = tr + i * 32;                        // n-local
      f32x4 v = *(const f32x4*)(Q + (size_t)(bn + r) * DM + bd + tc4);
      short4v h;
      h[0] = f2bf(v[0]); h[1] = f2bf(v[1]); h[2] = f2bf(v[2]); h[3] = f2bf(v[3]);
      *(short4v*)&tile[r][tc4] = h;
    }
    __syncthreads();
    #pragma unroll
    for (int i = 0; i < 2; ++i) {
      int r = tr + i * 32;                        // d-local
      short4v h;
      #pragma unroll
      for (int j = 0; j < 4; ++j) h[j] = tile[tc4 + j][r];
      *(short4v*)(Qt + (size_t)(bd + r) * NST + bn + tc4) = h;
    }
    __syncthreads();                              // X free again
  }

  // ---- phase 1: local scan (x_{-1}=0) streamed straight into LDS as bf16
  const float dt = expf(log_dt[0]);
  const float a  = expf(-dt * expf(Lam[tid]));
  const float g  = dt * Bv[tid];
  const float* up = u + ((size_t)b * SEQ + (size_t)c * TCH) * NST + tid;
  {
    float bufA[32], bufB[32];
    float x = 0.f;
    #define LOADB(BUF, BASE)                                        \
      _Pragma("unroll")                                             \
      for (int j = 0; j < 32; ++j) BUF[j] = up[(size_t)((BASE) + j) * NST];
    #define PROCB(BUF, BASE)                                        \
      _Pragma("unroll")                                             \
      for (int j = 0; j < 32; ++j) {                                \
        x = fmaf(a, x, g * BUF[j]);                                 \
        X[(BASE) + j][tid] = f2bf(x);                               \
      }
    LOADB(bufA, 0)
    LOADB(bufB, 32)
    PROCB(bufA, 0)
    LOADB(bufA, 64)
    PROCB(bufB, 32)
    LOADB(bufB, 96)
    PROCB(bufA, 64)
    PROCB(bufB, 96)
    #undef LOADB
    #undef PROCB
    S[(c * BATCH + b) * NST + tid] = x;           // chunk sum (local)
  }
  __threadfence();
  cg::this_grid().sync();

  // ---- phase 2: incoming state for this chunk from S[c'<c]
  float aT = a;
  #pragma unroll
  for (int i = 0; i < 7; ++i) aT *= aT;           // a^128
  float xin = 0.f;
  {
    int cp = 0;
    for (; cp + 8 <= c; cp += 8) {
      float sb[8];
      #pragma unroll
      for (int j = 0; j < 8; ++j) sb[j] = S[((cp + j) * BATCH + b) * NST + tid];
      #pragma unroll
      for (int j = 0; j < 8; ++j) xin = fmaf(aT, xin, sb[j]);
    }
    for (; cp < c; ++cp) xin = fmaf(aT, xin, S[(cp * BATCH + b) * NST + tid]);
  }

  // ---- phase 3: in-LDS correction x[t] = xl[t] + a^{t+1}*xin (same-thread column)
  {
    float ap = a;
    #pragma unroll 8
    for (int t = 0; t < TCH; ++t) {
      X[t][tid] = f2bf(fmaf(ap, xin, bf2f(X[t][tid])));
      ap *= a;
    }
  }
  __syncthreads();

  // ---- phase 4: GEMM 128x512x512 in TWO 64-row passes (acc[4][4], <=128 VGPR)
  const int lane = tid & 63;
  const int wc   = tid >> 6;                      // 0..7
  const int l15  = lane & 15;
  const int lhi  = lane >> 4;
  const int ka   = lhi * 8;
  const short* qbase = Qt + (size_t)(wc * 64 + l15) * NST + ka;
  float* yb = y + ((size_t)b * SEQ + (size_t)c * TCH) * DM;

  #pragma unroll
  for (int half = 0; half < 2; ++half) {
    const int r0 = half * 64;
    f32x4 acc[4][4];
    #pragma unroll
    for (int mi = 0; mi < 4; ++mi)
      #pragma unroll
      for (int nf = 0; nf < 4; ++nf) acc[mi][nf] = (f32x4){0.f, 0.f, 0.f, 0.f};

    #pragma unroll 4
    for (int kk = 0; kk < 16; ++kk) {
      const int k0 = kk * 32;
      short8v bfrag[4];
      #pragma unroll
      for (int nf = 0; nf < 4; ++nf)
        bfrag[nf] = *(const short8v*)(qbase + (size_t)nf * 16 * NST + k0);
      short8v afrag[4];
      #pragma unroll
      for (int mi = 0; mi < 4; ++mi)
        afrag[mi] = *(const short8v*)&X[r0 + mi * 16 + l15][k0 + ka];
      #pragma unroll
      for (int mi = 0; mi < 4; ++mi)
        #pragma unroll
        for (int nf = 0; nf < 4; ++nf)
          acc[mi][nf] = __builtin_amdgcn_mfma_f32_16x16x32_bf16(afrag[mi], bfrag[nf], acc[mi][nf], 0, 0, 0);
    }

    // y stores (nontemporal: y never re-read; keep u/Qt cache-resident)
    #pragma unroll
    for (int mi = 0; mi < 4; ++mi)
      #pragma unroll
      for (int nf = 0; nf < 4; ++nf) {
        const int rr = r0 + mi * 16 + lhi * 4;
        const int cc = wc * 64 + nf * 16 + l15;
        #pragma unroll
        for (int i = 0; i < 4; ++i)
          __builtin_nontemporal_store(acc[mi][nf][i], &yb[(size_t)(rr + i) * DM + cc]);
      }
  }
}

// ============================ FALLBACK (round-4 path) ============================
__global__ void k_scan_sums(const float* __restrict__ u, const float* __restrict__ Lam,
                            const float* __restrict__ Bv, const float* __restrict__ log_dt,
                            float* __restrict__ S) {
  int gid = blockIdx.x * 256 + threadIdx.x;
  int n2 = (gid & 255) * 2;
  int bc = gid >> 8;
  int b  = bc & (BATCH - 1);
  int c  = bc >> 3;
  float dt = expf(log_dt[0]);
  f32x2 lam = *(const f32x2*)(Lam + n2);
  f32x2 bv  = *(const f32x2*)(Bv + n2);
  float a0 = expf(-dt * expf(lam[0])), a1 = expf(-dt * expf(lam[1]));
  float g0 = dt * bv[0],               g1 = dt * bv[1];
  const float* up = u + ((size_t)b * SEQ + (size_t)c * TCH) * NST + n2;
  float s0 = 0.f, s1 = 0.f;
  #pragma unroll 8
  for (int t = 0; t < TCH; ++t) {
    f32x2 v = *(const f32x2*)(up + (size_t)t * NST);
    s0 = fmaf(a0, s0, g0 * v[0]);
    s1 = fmaf(a1, s1, g1 * v[1]);
  }
  *(f32x2*)(S + (c * BATCH + b) * NST + n2) = (f32x2){s0, s1};
}

__global__ void k_propagate(const float* __restrict__ Lam, const float* __restrict__ log_dt,
                            const float* __restrict__ S, float* __restrict__ Xc) {
  int gid = blockIdx.x * 256 + threadIdx.x;
  int n = gid & (NST - 1);
  int b = gid >> 9;
  float dt = expf(log_dt[0]);
  float a  = expf(-dt * expf(Lam[n]));
  float aT = a;
  #pragma unroll
  for (int i = 0; i < 7; ++i) aT *= aT;
  float x = 0.f;
  for (int c = 0; c < NCHUNK; ++c) {
    Xc[(c * BATCH + b) * NST + n] = x;
    x = fmaf(aT, x, S[(c * BATCH + b) * NST + n]);
  }
}

__global__ void k_transQ(const float* __restrict__ Q, short* __restrict__ Qt) {
  __shared__ short tile[64][68];
  int bn = (blockIdx.x & 7) * 64;
  int bd = (blockIdx.x >> 3) * 64;
  int tc = threadIdx.x & 15;
  int tr = threadIdx.x >> 4;
  #pragma unroll
  for (int i = 0; i < 4; ++i) {
    int r = tr + i * 16;
    f32x4 v = *(const f32x4*)(Q + (size_t)(bn + r) * DM + bd + tc * 4);
    short4v h;
    h[0] = f2bf(v[0]); h[1] = f2bf(v[1]); h[2] = f2bf(v[2]); h[3] = f2bf(v[3]);
    *(short4v*)&tile[r][tc * 4] = h;
  }
  __syncthreads();
  #pragma unroll
  for (int i = 0; i < 4; ++i) {
    int r = tr + i * 16;
    short4v h;
    #pragma unroll
    for (int j = 0; j < 4; ++j) h[j] = tile[tc * 4 + j][r];
    *(short4v*)(Qt + (size_t)(bd + r) * NST + bn + tc * 4) = h;
  }
}

__global__ __launch_bounds__(512) void k_fused(
    const float* __restrict__ u, const float* __restrict__ Lam,
    const float* __restrict__ Bv, const float* __restrict__ log_dt,
    const float* __restrict__ Xc, const short* __restrict__ Qt,
    float* __restrict__ y) {
  __shared__ __align__(16) short X[2][64][LDP];
  const int tid = threadIdx.x;
  const int b = blockIdx.x & (BATCH - 1);
  const int c = blockIdx.x >> 3;
  const float dt = expf(log_dt[0]);
  const float a  = expf(-dt * expf(Lam[tid]));
  const float g  = dt * Bv[tid];
  float x = Xc[(c * BATCH + b) * NST + tid];
  const float* up = u + ((size_t)b * SEQ + (size_t)c * TCH) * NST + tid;
  {
    float ur[64];
    #pragma unroll
    for (int t = 0; t < 64; ++t) ur[t] = up[(size_t)t * NST];
    #pragma unroll
    for (int t = 0; t < 64; ++t) { x = fmaf(a, x, g * ur[t]); X[0][t][tid] = f2bf(x); }
  }
  __syncthreads();
  const int lane = tid & 63;
  const int wc   = tid >> 6;
  const int l15  = lane & 15;
  const int lhi  = lane >> 4;
  const int ka   = lhi * 8;
  const short* qbase = Qt + (size_t)(wc * 64 + l15) * NST + ka;
  float* yb = y + ((size_t)b * SEQ + (size_t)c * TCH) * DM;
  float ur2[64];
  f32x4 acc[4][4];
  #pragma unroll
  for (int mi = 0; mi < 4; ++mi)
    #pragma unroll
    for (int nf = 0; nf < 4; ++nf) acc[mi][nf] = (f32x4){0.f, 0.f, 0.f, 0.f};
  #pragma unroll
  for (int kk = 0; kk < 16; ++kk) {
    const int k0 = kk * 32;
    #pragma unroll
    for (int j = 0; j < 4; ++j) ur2[kk * 4 + j] = up[(size_t)(64 + kk * 4 + j) * NST];
    short8v afrag[4];
    #pragma unroll
    for (int mi = 0; mi < 4; ++mi) afrag[mi] = *(const short8v*)&X[0][mi * 16 + l15][k0 + ka];
    short8v bfrag[4];
    #pragma unroll
    for (int nf = 0; nf < 4; ++nf) bfrag[nf] = *(const short8v*)(qbase + (size_t)nf * 16 * NST + k0);
    #pragma unroll
    for (int mi = 0; mi < 4; ++mi)
      #pragma unroll
      for (int nf = 0; nf < 4; ++nf)
        acc[mi][nf] = __builtin_amdgcn_mfma_f32_16x16x32_bf16(afrag[mi], bfrag[nf], acc[mi][nf], 0, 0, 0);
  }
  #pragma unroll
  for (int mi = 0; mi < 4; ++mi)
    #pragma unroll
    for (int nf = 0; nf < 4; ++nf) {
      const int rr = mi * 16 + lhi * 4;
      const int cc = wc * 64 + nf * 16 + l15;
      #pragma unroll
      for (int i = 0; i < 4; ++i) yb[(size_t)(rr + i) * DM + cc] = acc[mi][nf][i];
    }
  #pragma unroll
  for (int t = 0; t < 64; ++t) { x = fmaf(a, x, g * ur2[t]); X[1][t][tid] = f2bf(x); }
  __syncthreads();
  #pragma unroll
  for (int mi = 0; mi < 4; ++mi)
    #pragma unroll
    for (int nf = 0; nf < 4; ++nf) acc[mi][nf] = (f32x4){0.f, 0.f, 0.f, 0.f};
  #pragma unroll
  for (int kk = 0; kk < 16; ++kk) {
    const int k0 = kk * 32;
    short8v afrag[4];
    #pragma unroll
    for (int mi = 0; mi < 4; ++mi) afrag[mi] = *(const short8v*)&X[1][mi * 16 + l15][k0 + ka];
    short8v bfrag[4];
    #pragma unroll
    for (int nf = 0; nf < 4; ++nf) bfrag[nf] = *(const short8v*)(qbase + (size_t)nf * 16 * NST + k0);
    #pragma unroll
    for (int mi = 0; mi < 4; ++mi)
      #pragma unroll
      for (int nf = 0; nf < 4; ++nf)
        acc[mi][nf] = __builtin_amdgcn_mfma_f32_16x16x32_bf16(afrag[mi], bfrag[nf], acc[mi][nf], 0, 0, 0);
  }
  #pragma unroll
  for (int mi = 0; mi < 4; ++mi)
    #pragma unroll
    for (int nf = 0; nf < 4; ++nf) {
      const int rr = 64 + mi * 16 + lhi * 4;
      const int cc = wc * 64 + nf * 16 + l15;
      #pragma unroll
      for (int i = 0; i < 4; ++i) yb[(size_t)(rr + i) * DM + cc] = acc[mi][nf][i];
    }
}

extern "C" void kernel_launch(void* const* d_in, const int* in_sizes, int n_in,
                              void* d_out, int out_size, void* d_ws, size_t ws_size,
                              hipStream_t stream) {
  const float* u      = (const float*)d_in[0];
  const float* Lam    = (const float*)d_in[1];
  const float* Bv     = (const float*)d_in[2];
  const float* Q      = (const float*)d_in[3];
  const float* log_dt = (const float*)d_in[4];
  float* out = (float*)d_out;

  float* S  = (float*)d_ws;                                  // 512 KB
  float* Xc = S + NCHUNK * BATCH * NST;                      // 512 KB (fallback only)
  short* Qt = (short*)(Xc + NCHUNK * BATCH * NST);           // 512 KB bf16

  void* args[] = {(void*)&u, (void*)&Lam, (void*)&Bv, (void*)&log_dt,
                  (void*)&Q, (void*)&S, (void*)&Qt, (void*)&out};
  hipError_t e = hipLaunchCooperativeKernel((const void*)k_mega,
                                            dim3(NCHUNK * BATCH), dim3(512),
                                            args, 0, stream);
  if (e != hipSuccess) {
    // fallback: proven round-4 four-kernel path (identical output)
    hipLaunchKernelGGL(k_scan_sums, dim3(NCHUNK * BATCH), dim3(256), 0, stream,
                       u, Lam, Bv, log_dt, S);
    hipLaunchKernelGGL(k_propagate, dim3(BATCH * NST / 256), dim3(256), 0, stream,
                       Lam, log_dt, S, Xc);
    hipLaunchKernelGGL(k_transQ, dim3(64), dim3(256), 0, stream, Q, Qt);
    hipLaunchKernelGGL(k_fused, dim3(NCHUNK * BATCH), dim3(512), 0, stream,
                       u, Lam, Bv, log_dt, Xc, Qt, out);
  }
}

// Round 9
// 69.969 us; speedup vs baseline: 2.2646x; 2.2646x over previous
//
#include <hip/hip_runtime.h>
#include <hip/hip_bf16.h>

#define BATCH 8
#define SEQ   4096
#define NST   512     // state dim == GEMM K
#define DM    512     // d_model  == GEMM N
#define NCHUNK 64
#define TCH    64     // SEQ / NCHUNK
#define LDP    (NST + 8)   // LDS row pitch in shorts (2-way bank alias only)

typedef __attribute__((ext_vector_type(4))) float f32x4;
typedef __attribute__((ext_vector_type(2))) float f32x2;
typedef __attribute__((ext_vector_type(8))) short short8v;   // 8 bf16
typedef __attribute__((ext_vector_type(4))) short short4v;

__device__ __forceinline__ short f2bf(float f) {
  union { float f; unsigned u; } v; v.f = f;
  unsigned r = v.u + 0x7FFFu + ((v.u >> 16) & 1u);   // RNE truncate to bf16
  return (short)(r >> 16);
}

// K1: per-chunk local scan sums S[c][b][n], f32x2 per thread
__global__ void k_scan_sums(const float* __restrict__ u, const float* __restrict__ Lam,
                            const float* __restrict__ Bv, const float* __restrict__ log_dt,
                            float* __restrict__ S) {
  int gid = blockIdx.x * 256 + threadIdx.x;      // [0, NCHUNK*BATCH*256)
  int n2 = (gid & 255) * 2;
  int bc = gid >> 8;
  int b  = bc & (BATCH - 1);
  int c  = bc >> 3;
  float dt = expf(log_dt[0]);
  f32x2 lam = *(const f32x2*)(Lam + n2);
  f32x2 bv  = *(const f32x2*)(Bv + n2);
  float a0 = expf(-dt * expf(lam[0])), a1 = expf(-dt * expf(lam[1]));
  float g0 = dt * bv[0],               g1 = dt * bv[1];
  const float* up = u + ((size_t)b * SEQ + (size_t)c * TCH) * NST + n2;
  float s0 = 0.f, s1 = 0.f;
  #pragma unroll 8
  for (int t = 0; t < TCH; ++t) {
    f32x2 v = *(const f32x2*)(up + (size_t)t * NST);
    s0 = fmaf(a0, s0, g0 * v[0]);
    s1 = fmaf(a1, s1, g1 * v[1]);
  }
  *(f32x2*)(S + (c * BATCH + b) * NST + n2) = (f32x2){s0, s1};
}

// K2: sequential chunk-state propagation: Xc[c] = incoming state of chunk c
__global__ void k_propagate(const float* __restrict__ Lam, const float* __restrict__ log_dt,
                            const float* __restrict__ S, float* __restrict__ Xc) {
  int gid = blockIdx.x * 256 + threadIdx.x;      // [0, BATCH*NST)
  int n = gid & (NST - 1);
  int b = gid >> 9;
  float dt = expf(log_dt[0]);
  float a  = expf(-dt * expf(Lam[n]));
  float aT = a;
  #pragma unroll
  for (int i = 0; i < 6; ++i) aT *= aT;          // a^64 = a^TCH
  float x = 0.f;
  for (int c = 0; c < NCHUNK; ++c) {
    Xc[(c * BATCH + b) * NST + n] = x;
    x = fmaf(aT, x, S[(c * BATCH + b) * NST + n]);
  }
}

// K3: Qt[d][n] = bf16(Q[n][d]) via LDS tile transpose (coalesced both sides)
__global__ void k_transQ(const float* __restrict__ Q, short* __restrict__ Qt) {
  __shared__ short tile[64][68];
  int bn = (blockIdx.x & 7) * 64;                // n tile base
  int bd = (blockIdx.x >> 3) * 64;               // d tile base
  int tc = threadIdx.x & 15;                     // 16 col-quads
  int tr = threadIdx.x >> 4;                     // 16 rows per pass
  #pragma unroll
  for (int i = 0; i < 4; ++i) {
    int r = tr + i * 16;                         // n-local
    f32x4 v = *(const f32x4*)(Q + (size_t)(bn + r) * DM + bd + tc * 4);
    short4v h;
    h[0] = f2bf(v[0]); h[1] = f2bf(v[1]); h[2] = f2bf(v[2]); h[3] = f2bf(v[3]);
    *(short4v*)&tile[r][tc * 4] = h;
  }
  __syncthreads();
  #pragma unroll
  for (int i = 0; i < 4; ++i) {
    int r = tr + i * 16;                         // d-local
    short4v h;
    #pragma unroll
    for (int j = 0; j < 4; ++j) h[j] = tile[tc * 4 + j][r];
    *(short4v*)(Qt + (size_t)(bd + r) * NST + bn + tc * 4) = h;
  }
}

// K4 fused: seeded 64-row scan -> LDS bf16 -> single-pass 64x512x512 GEMM -> y.
// LDS 66.5 KB + VGPR <=128 -> 2 blocks/CU (16 waves/CU, 4 waves/SIMD): the
// co-resident block's GEMM/store phase hides this block's u-load latency.
// NOTE: no min-waves launch_bounds arg (round 3's (512,4) forced VGPR=64 and
// spilled the 104-reg GEMM working set; natural allocation fits ~92-120).
__global__ __launch_bounds__(512) void k_fused(
    const float* __restrict__ u, const float* __restrict__ Lam,
    const float* __restrict__ Bv, const float* __restrict__ log_dt,
    const float* __restrict__ Xc, const short* __restrict__ Qt,
    float* __restrict__ y) {
  __shared__ __align__(16) short X[TCH][LDP];    // 64 x 520 shorts = 66560 B
  const int tid = threadIdx.x;
  const int b = blockIdx.x & (BATCH - 1);
  const int c = blockIdx.x >> 3;

  // ---- phase 1: seeded scan, burst-load 64 u values then serial chain ----
  {
    const float dt = expf(log_dt[0]);
    const float a  = expf(-dt * expf(Lam[tid]));
    const float g  = dt * Bv[tid];
    float x  = Xc[(c * BATCH + b) * NST + tid];
    const float* up = u + ((size_t)b * SEQ + (size_t)c * TCH) * NST + tid;
    float ur[TCH];
    #pragma unroll
    for (int t = 0; t < TCH; ++t) ur[t] = up[(size_t)t * NST];
    #pragma unroll
    for (int t = 0; t < TCH; ++t) {
      x = fmaf(a, x, g * ur[t]);
      X[t][tid] = f2bf(x);
    }
  }
  __syncthreads();

  // ---- phase 2: GEMM 64x512x512; wave wc owns 64 cols x all 64 rows ----
  const int lane = tid & 63;
  const int wc   = tid >> 6;                     // 0..7
  const int l15  = lane & 15;
  const int lhi  = lane >> 4;
  const int ka   = lhi * 8;                      // k offset within BK=32
  const short* qbase = Qt + (size_t)(wc * 64 + l15) * NST + ka;
  float* yb = y + ((size_t)b * SEQ + (size_t)c * TCH) * DM;

  f32x4 acc[4][4];
  #pragma unroll
  for (int mi = 0; mi < 4; ++mi)
    #pragma unroll
    for (int nf = 0; nf < 4; ++nf) acc[mi][nf] = (f32x4){0.f, 0.f, 0.f, 0.f};

  #pragma unroll 4
  for (int kk = 0; kk < 16; ++kk) {
    const int k0 = kk * 32;
    short8v afrag[4];
    #pragma unroll
    for (int mi = 0; mi < 4; ++mi)
      afrag[mi] = *(const short8v*)&X[mi * 16 + l15][k0 + ka];
    short8v bfrag[4];
    #pragma unroll
    for (int nf = 0; nf < 4; ++nf)
      bfrag[nf] = *(const short8v*)(qbase + (size_t)nf * 16 * NST + k0);
    #pragma unroll
    for (int mi = 0; mi < 4; ++mi)
      #pragma unroll
      for (int nf = 0; nf < 4; ++nf)
        acc[mi][nf] = __builtin_amdgcn_mfma_f32_16x16x32_bf16(afrag[mi], bfrag[nf], acc[mi][nf], 0, 0, 0);
  }

  // ---- y stores: each (mi,nf,i) instr = 4 rows x 16 consecutive cols (64B segs) ----
  #pragma unroll
  for (int mi = 0; mi < 4; ++mi)
    #pragma unroll
    for (int nf = 0; nf < 4; ++nf) {
      const int rr = mi * 16 + lhi * 4;
      const int cc = wc * 64 + nf * 16 + l15;
      #pragma unroll
      for (int i = 0; i < 4; ++i)
        yb[(size_t)(rr + i) * DM + cc] = acc[mi][nf][i];
    }
}

extern "C" void kernel_launch(void* const* d_in, const int* in_sizes, int n_in,
                              void* d_out, int out_size, void* d_ws, size_t ws_size,
                              hipStream_t stream) {
  const float* u      = (const float*)d_in[0];
  const float* Lam    = (const float*)d_in[1];
  const float* Bv     = (const float*)d_in[2];
  const float* Q      = (const float*)d_in[3];
  const float* log_dt = (const float*)d_in[4];
  float* out = (float*)d_out;

  float* S  = (float*)d_ws;                                  // 1 MB
  float* Xc = S + NCHUNK * BATCH * NST;                      // 1 MB
  short* Qt = (short*)(Xc + NCHUNK * BATCH * NST);           // 512 KB bf16

  hipLaunchKernelGGL(k_transQ, dim3(64), dim3(256), 0, stream, Q, Qt);
  hipLaunchKernelGGL(k_scan_sums, dim3(NCHUNK * BATCH), dim3(256), 0, stream,
                     u, Lam, Bv, log_dt, S);
  hipLaunchKernelGGL(k_propagate, dim3(BATCH * NST / 256), dim3(256), 0, stream,
                     Lam, log_dt, S, Xc);
  hipLaunchKernelGGL(k_fused, dim3(NCHUNK * BATCH), dim3(512), 0, stream,
                     u, Lam, Bv, log_dt, Xc, Qt, out);
}